// Round 9
// baseline (345.109 us; speedup 1.0000x reference)
//
#include <hip/hip_runtime.h>
#include <math.h>

#define BB   4
#define SS   2048
#define EE   256
#define HH   8
#define DD   32
#define WW   33
#define KKN  (SS - WW + 1)   // 2016
#define SCALE 0.17677669529663687f  // 1/sqrt(32)
#define FMAX 20.0f           // fixed softmax max: p = exp(s - FMAX); cancels in p/l

typedef __attribute__((ext_vector_type(8))) short short8v;   // 8 bf16 MFMA A/B frag
typedef __attribute__((ext_vector_type(4))) short short4v;
typedef __attribute__((ext_vector_type(4))) float float4v;   // MFMA C/D frag

__device__ __forceinline__ short f2bf(float f) {
    union { float f; unsigned u; } v; v.f = f;
    unsigned r = (v.u + 0x7fffu + ((v.u >> 16) & 1u)) >> 16;  // RNE
    return (short)r;
}

// ---------------------------------------------------------------------------
// Kernel 1: QKV projection as LDS-tiled GEMM. C(8192x768) = x(8192x256)*Wcat.
// Grid (128 row-tiles, 12 col-tiles); each col-tile lies in exactly one of
// Wq/Wk/Wv. Per-output FMA chain and e-order identical to R8 -> bit-identical.
// ---------------------------------------------------------------------------
__global__ __launch_bounds__(256) void qkv_kernel(
    const float* __restrict__ x,
    const float* __restrict__ Wq, const float* __restrict__ bq,
    const float* __restrict__ Wk, const float* __restrict__ bk,
    const float* __restrict__ Wv, const float* __restrict__ bv,
    short* __restrict__ qo, short* __restrict__ ko, float* __restrict__ vo)
{
    __shared__ alignas(16) float xs[64][68];
    __shared__ alignas(16) float ws[64][68];

    const int t   = threadIdx.x;
    const int r0  = blockIdx.x * 64;     // row tile
    const int ct  = blockIdx.y;          // col tile 0..11
    const int mat = ct >> 2;             // 0=q 1=k 2=v
    const int cm0 = (ct & 3) * 64;       // col base within the matrix
    const float* Wm   = (mat == 0) ? Wq : (mat == 1) ? Wk : Wv;
    const float* bias = (mat == 0) ? bq : (mat == 1) ? bk : bv;

    const int tr = t >> 4, tc = t & 15;  // 16x16 thread grid; 4x4 outputs each

    float acc[4][4];
#pragma unroll
    for (int i = 0; i < 4; i++)
#pragma unroll
        for (int j = 0; j < 4; j++) acc[i][j] = 0.f;

    for (int ec = 0; ec < 4; ec++) {
        const int e0 = ec * 64;
        __syncthreads();   // previous chunk's compute done before overwrite
#pragma unroll
        for (int i = 0; i < 4; i++) {
            int L = t + i * 256;               // 0..1023
            int r = L >> 4, c4 = (L & 15) * 4;
            *(float4*)&xs[r][c4] = *(const float4*)(x  + (size_t)(r0 + r) * EE + e0 + c4);
            *(float4*)&ws[r][c4] = *(const float4*)(Wm + (size_t)(e0 + r) * EE + cm0 + c4);
        }
        __syncthreads();

#pragma unroll
        for (int eg = 0; eg < 16; eg++) {
            float4 xv[4], wv4[4];
#pragma unroll
            for (int i = 0; i < 4; i++) xv[i]  = *(const float4*)&xs[tr * 4 + i][eg * 4];
#pragma unroll
            for (int j = 0; j < 4; j++) wv4[j] = *(const float4*)&ws[eg * 4 + j][tc * 4];
            const float* w0p = (const float*)&wv4[0];
            const float* w1p = (const float*)&wv4[1];
            const float* w2p = (const float*)&wv4[2];
            const float* w3p = (const float*)&wv4[3];
#pragma unroll
            for (int i = 0; i < 4; i++)
#pragma unroll
                for (int j = 0; j < 4; j++)
                    acc[i][j] = acc[i][j] + xv[i].x * w0p[j] + xv[i].y * w1p[j]
                                          + xv[i].z * w2p[j] + xv[i].w * w3p[j];
        }
    }

    // epilogue: cols cm = cm0 + tc*4 + j (j=0..3 stay within one head)
    const int cmb = cm0 + tc * 4;
    const int h = cmb >> 5, d0 = cmb & 31;
    float b4[4];
#pragma unroll
    for (int j = 0; j < 4; j++) b4[j] = bias[cmb + j];

#pragma unroll
    for (int i = 0; i < 4; i++) {
        int row = r0 + tr * 4 + i;
        int b_  = row >> 11;
        int s   = row & 2047;
        size_t o = (((size_t)(b_ * HH + h)) * SS + s) * DD + d0;
        if (mat == 2) {
            float4 vv;
            vv.x = acc[i][0] + b4[0]; vv.y = acc[i][1] + b4[1];
            vv.z = acc[i][2] + b4[2]; vv.w = acc[i][3] + b4[3];
            *(float4*)(vo + o) = vv;
        } else {
            short4v sv;
            sv.x = f2bf(acc[i][0] + b4[0]); sv.y = f2bf(acc[i][1] + b4[1]);
            sv.z = f2bf(acc[i][2] + b4[2]); sv.w = f2bf(acc[i][3] + b4[3]);
            *(short4v*)(((mat == 0) ? qo : ko) + o) = sv;
        }
    }
}

// ---------------------------------------------------------------------------
// Kernel 2: sliding-window sum of V -> transposed bf16 vsT[bh][d][kk]. (unchanged)
// ---------------------------------------------------------------------------
__global__ __launch_bounds__(256) void vs_kernel(
    const float* __restrict__ v, short* __restrict__ vsT)
{
    const int t   = threadIdx.x;
    const int d4  = t & 7;
    const int kkb = blockIdx.x * 32 + (t >> 3);
    const int bh  = blockIdx.y;
    if (kkb >= 252) return;
    const int kb0 = kkb * 8;

    const float4* vp = (const float4*)(v + ((size_t)bh * SS + kb0) * DD) + d4;
    float4 rbuf[7];
    float4 acc = {0.f, 0.f, 0.f, 0.f};
#pragma unroll
    for (int w = 0; w < WW; w++) {
        float4 xv = vp[w * 8];
        if (w < 7) rbuf[w] = xv;
        acc.x += xv.x; acc.y += xv.y; acc.z += xv.z; acc.w += xv.w;
    }
    short8v sh[4];
    sh[0][0] = f2bf(acc.x); sh[1][0] = f2bf(acc.y);
    sh[2][0] = f2bf(acc.z); sh[3][0] = f2bf(acc.w);
#pragma unroll
    for (int s = 1; s < 8; s++) {
        float4 sub = rbuf[s - 1];
        float4 add = vp[(s + 32) * 8];
        acc.x += add.x - sub.x; acc.y += add.y - sub.y;
        acc.z += add.z - sub.z; acc.w += add.w - sub.w;
        sh[0][s] = f2bf(acc.x); sh[1][s] = f2bf(acc.y);
        sh[2][s] = f2bf(acc.z); sh[3][s] = f2bf(acc.w);
    }
#pragma unroll
    for (int j = 0; j < 4; j++) {
        short* op = vsT + ((size_t)bh * DD + 4 * d4 + j) * KKN + kb0;
        *(short8v*)op = sh[j];
    }
}

// ---------------------------------------------------------------------------
// Kernel 3: flash attention (R7 structure; 64-row K ring; pb unioned onto Qb;
// LDS 24.7 KB -> 6 blocks/CU).
// ---------------------------------------------------------------------------
__global__ __launch_bounds__(256, 6) void attn_kernel(
    const short* __restrict__ qg, const short* __restrict__ kg,
    const short* __restrict__ vsTg, float* __restrict__ out)
{
    __shared__ alignas(16) short QbS[64][40];      // Qext; reused as pb after hoist
    __shared__ alignas(16) short Kb[64][40];       // 64-row K ring
    __shared__ alignas(16) short Gst[64][72];      // bf16 skewed Gram (row 63 = pad)
    __shared__ alignas(16) short vT[2][32][40];    // double-buffered vs tile [d][ki]
    __shared__ float lrow[32];

    short (*Qb)[40] = QbS;
    short (*pb)[40] = QbS;   // union: Qb dead after pre-loop hoist (barrier-ordered)

    const int t  = threadIdx.x;
    const int qt = blockIdx.x;
    const int bh = blockIdx.y;
    const int q0 = qt * 32;

    const short* qb   = qg   + (size_t)bh * SS * DD;
    const short* kb   = kg   + (size_t)bh * SS * DD;
    const short* vsTb = vsTg + (size_t)bh * DD * KKN;

    const int lane = t & 63, wv = t >> 6;
    const int quad = lane >> 4, lr = lane & 15;
    const int ptm = wv >> 1, ptn = wv & 1;

    // ---- zero-init Gst (garbage containment for the U-matmul) ----
    {
        short8v z = {0, 0, 0, 0, 0, 0, 0, 0};
        short* g = &Gst[0][0];
        for (int i = t; i < 576; i += 256) *(short8v*)(g + 8 * i) = z;
    }

    // ---- initial staging: Qext (64 rows) + K rows 0..63 ----
    {
        int row = t >> 2, c8 = (t & 3) * 8;
        int gq = q0 - 16 + row;
        if (gq >= 0 && gq < SS) {
            *(short8v*)&Qb[row][c8] = *(const short8v*)(qb + (size_t)gq * DD + c8);
        } else {
            float4 z = {0.f, 0.f, 0.f, 0.f};
            *(float4*)&Qb[row][c8] = z;
        }
        *(short8v*)&Kb[row][c8] = *(const short8v*)(kb + (size_t)row * DD + c8);
    }
    if (t < 32) lrow[t] = 0.f;
    __syncthreads();

    // ---- hoist loop-invariant Q B-frags (Qb dead afterwards) ----
    short8v Qf[4];
#pragma unroll
    for (int tq = 0; tq < 4; tq++)
        Qf[tq] = *(const short8v*)&Qb[tq * 16 + lr][quad * 8];

    // ---- banded-ones U-frags: U[m][qi] = 1 iff qi <= m <= qi+32 ----
    short8v Uf[2][2];
#pragma unroll
    for (int qit = 0; qit < 2; qit++)
#pragma unroll
        for (int ch = 0; ch < 2; ch++) {
            short8v u;
#pragma unroll
            for (int j = 0; j < 8; j++) {
                int m  = ch * 32 + quad * 8 + j;
                int qi = qit * 16 + lr;
                u[j] = (qi <= m && m <= qi + 32) ? (short)0x3F80 : (short)0;
            }
            Uf[qit][ch] = u;
        }

    float4v acc = {0.f, 0.f, 0.f, 0.f};
    float lsum[2] = {0.f, 0.f};

    for (int kt = 0; kt < 63; kt++) {
        // ================= Phase A =================
        if (t >= 128) {
            int u = t - 128;
            int d_ = u >> 2, c8 = (u & 3) * 8;
            *(short8v*)&vT[kt & 1][d_][c8] =
                *(const short8v*)(vsTb + (size_t)d_ * KKN + kt * 32 + c8);
        }

        // Gram MFMA (A = K-frag, B = Q-frag) -> bf16 skewed store
        {
            const int srow = (kt * 32 + wv * 16 + lr) & 63;
            const short8v A = *(const short8v*)&Kb[srow][quad * 8];
#pragma unroll
            for (int tq = 0; tq < 4; tq++) {
                if ((tq == 0 && wv == 3) || (tq == 3 && wv == 0)) continue;  // dead
                float4v c0 = {0.f, 0.f, 0.f, 0.f};
                c0 = __builtin_amdgcn_mfma_f32_16x16x32_bf16(A, Qf[tq], c0, 0, 0, 0);
                const int m = tq * 16 + lr;
#pragma unroll
                for (int e = 0; e < 4; e++) {
                    int n  = wv * 16 + quad * 4 + e;
                    int j2 = n - m + 31;
                    if ((unsigned)j2 < 63u) Gst[j2][m] = f2bf(c0[e]);
                }
            }
        }

        // PV for PREVIOUS iter
        if (kt > 0) {
            const short8v Ap = *(const short8v*)&pb[ptm * 16 + lr][quad * 8];
            const short8v Bv = *(const short8v*)&vT[(kt - 1) & 1][ptn * 16 + lr][quad * 8];
            acc = __builtin_amdgcn_mfma_f32_16x16x32_bf16(Ap, Bv, acc, 0, 0, 0);
        }
        __syncthreads();   // [A] Gst complete; Kb/pb/vT consumed

        // ================= Phase B =================
        // ring prefetch: rows kt*32+64 .. +95 land in the 32 dead slots
        if (kt < 62 && t >= 128) {
            int u = t - 128;
            int r2 = u >> 2, c8 = (u & 3) * 8;
            int g  = kt * 32 + 64 + r2;
            *(short8v*)&Kb[g & 63][c8] = *(const short8v*)(kb + (size_t)g * DD + c8);
        }

        // S_skew = Gst x U via MFMA; p = exp(S*SCALE - FMAX) -> pb (ki-masked)
        {
            const int jrow = wv * 16 + lr;
            const short8v A0f = *(const short8v*)&Gst[jrow][quad * 8];
            const short8v A1f = *(const short8v*)&Gst[jrow][32 + quad * 8];
            const int kib = lr + wv * 16 + quad * 4 - 31;
#pragma unroll
            for (int qit = 0; qit < 2; qit++) {
                float4v D = {0.f, 0.f, 0.f, 0.f};
                D = __builtin_amdgcn_mfma_f32_16x16x32_bf16(A0f, Uf[qit][0], D, 0, 0, 0);
                D = __builtin_amdgcn_mfma_f32_16x16x32_bf16(A1f, Uf[qit][1], D, 0, 0, 0);
                const int qi = qit * 16 + lr;
#pragma unroll
                for (int e = 0; e < 4; e++) {
                    int ki = kib + qit * 16 + e;
                    if ((unsigned)ki < 32u) {
                        float p = __expf(fmaf(D[e], SCALE, -FMAX));
                        pb[qi][ki] = f2bf(p);
                        lsum[qit] += p;
                    }
                }
            }
        }
        __syncthreads();   // [B] pb ready; ring prefetch visible
    }

    // ---- final PV (kt = 62) ----
    {
        const short8v Ap = *(const short8v*)&pb[ptm * 16 + lr][quad * 8];
        const short8v Bv = *(const short8v*)&vT[0][ptn * 16 + lr][quad * 8];   // 62&1==0
        acc = __builtin_amdgcn_mfma_f32_16x16x32_bf16(Ap, Bv, acc, 0, 0, 0);
    }

    // ---- l reduction: cross-quad shuffle then one atomic per (wave, qit) ----
#pragma unroll
    for (int qit = 0; qit < 2; qit++) {
        float s = lsum[qit];
        s += __shfl_xor(s, 16);
        s += __shfl_xor(s, 32);
        if (quad == 0) atomicAdd(&lrow[qit * 16 + lr], s);
    }
    __syncthreads();

    // ---- epilogue ----
    {
        const int rrow = ptm * 16 + quad * 4;
        const int col  = ptn * 16 + lr;
        const int b_ = bh >> 3, h = bh & 7;
#pragma unroll
        for (int e = 0; e < 4; e++) {
            int s_ = q0 + rrow + e;
            out[((size_t)(b_ * SS + s_)) * EE + h * DD + col] = acc[e] / lrow[rrow + e];
        }
    }
}

// ---------------------------------------------------------------------------
extern "C" void kernel_launch(void* const* d_in, const int* in_sizes, int n_in,
                              void* d_out, int out_size, void* d_ws, size_t ws_size,
                              hipStream_t stream)
{
    (void)in_sizes; (void)n_in; (void)out_size; (void)ws_size;
    const float* x  = (const float*)d_in[0];
    const float* Wq = (const float*)d_in[1];
    const float* bq = (const float*)d_in[2];
    const float* Wk = (const float*)d_in[3];
    const float* bk = (const float*)d_in[4];
    const float* Wv = (const float*)d_in[5];
    const float* bv = (const float*)d_in[6];
    float* out = (float*)d_out;

    const size_t REG = (size_t)BB * HH * SS * DD;   // 2,097,152
    short* qbf   = (short*)d_ws;
    short* kbf   = qbf + REG;
    float* vbuf  = (float*)(kbf + REG);
    short* vsTb  = (short*)(vbuf + REG);            // 32*32*2016 shorts

    qkv_kernel<<<dim3(128, 12), dim3(256), 0, stream>>>(x, Wq, bq, Wk, bk, Wv, bv,
                                                        qbf, kbf, vbuf);
    vs_kernel<<<dim3(8, 32), dim3(256), 0, stream>>>(vbuf, vsTb);
    attn_kernel<<<dim3(64, 32), dim3(256), 0, stream>>>(qbf, kbf, vsTb, out);
}

// Round 10
// 326.985 us; speedup vs baseline: 1.0554x; 1.0554x over previous
//
#include <hip/hip_runtime.h>
#include <math.h>

#define BB   4
#define SS   2048
#define EE   256
#define HH   8
#define DD   32
#define WW   33
#define KKN  (SS - WW + 1)   // 2016
#define SCALE 0.17677669529663687f  // 1/sqrt(32)
#define FMAX 20.0f           // fixed softmax max: p = exp(s - FMAX); cancels in p/l

typedef __attribute__((ext_vector_type(8))) short short8v;   // 8 bf16 MFMA A/B frag
typedef __attribute__((ext_vector_type(4))) short short4v;
typedef __attribute__((ext_vector_type(4))) float float4v;   // MFMA C/D frag

__device__ __forceinline__ short f2bf(float f) {
    union { float f; unsigned u; } v; v.f = f;
    unsigned r = (v.u + 0x7fffu + ((v.u >> 16) & 1u)) >> 16;  // RNE
    return (short)r;
}

// ---------------------------------------------------------------------------
// Kernel 1: QKV projection as LDS-tiled GEMM (R9, unchanged).
// ---------------------------------------------------------------------------
__global__ __launch_bounds__(256) void qkv_kernel(
    const float* __restrict__ x,
    const float* __restrict__ Wq, const float* __restrict__ bq,
    const float* __restrict__ Wk, const float* __restrict__ bk,
    const float* __restrict__ Wv, const float* __restrict__ bv,
    short* __restrict__ qo, short* __restrict__ ko, float* __restrict__ vo)
{
    __shared__ alignas(16) float xs[64][68];
    __shared__ alignas(16) float ws[64][68];

    const int t   = threadIdx.x;
    const int r0  = blockIdx.x * 64;
    const int ct  = blockIdx.y;
    const int mat = ct >> 2;
    const int cm0 = (ct & 3) * 64;
    const float* Wm   = (mat == 0) ? Wq : (mat == 1) ? Wk : Wv;
    const float* bias = (mat == 0) ? bq : (mat == 1) ? bk : bv;

    const int tr = t >> 4, tc = t & 15;

    float acc[4][4];
#pragma unroll
    for (int i = 0; i < 4; i++)
#pragma unroll
        for (int j = 0; j < 4; j++) acc[i][j] = 0.f;

    for (int ec = 0; ec < 4; ec++) {
        const int e0 = ec * 64;
        __syncthreads();
#pragma unroll
        for (int i = 0; i < 4; i++) {
            int L = t + i * 256;
            int r = L >> 4, c4 = (L & 15) * 4;
            *(float4*)&xs[r][c4] = *(const float4*)(x  + (size_t)(r0 + r) * EE + e0 + c4);
            *(float4*)&ws[r][c4] = *(const float4*)(Wm + (size_t)(e0 + r) * EE + cm0 + c4);
        }
        __syncthreads();

#pragma unroll
        for (int eg = 0; eg < 16; eg++) {
            float4 xv[4], wv4[4];
#pragma unroll
            for (int i = 0; i < 4; i++) xv[i]  = *(const float4*)&xs[tr * 4 + i][eg * 4];
#pragma unroll
            for (int j = 0; j < 4; j++) wv4[j] = *(const float4*)&ws[eg * 4 + j][tc * 4];
            const float* w0p = (const float*)&wv4[0];
            const float* w1p = (const float*)&wv4[1];
            const float* w2p = (const float*)&wv4[2];
            const float* w3p = (const float*)&wv4[3];
#pragma unroll
            for (int i = 0; i < 4; i++)
#pragma unroll
                for (int j = 0; j < 4; j++)
                    acc[i][j] = acc[i][j] + xv[i].x * w0p[j] + xv[i].y * w1p[j]
                                          + xv[i].z * w2p[j] + xv[i].w * w3p[j];
        }
    }

    const int cmb = cm0 + tc * 4;
    const int h = cmb >> 5, d0 = cmb & 31;
    float b4[4];
#pragma unroll
    for (int j = 0; j < 4; j++) b4[j] = bias[cmb + j];

#pragma unroll
    for (int i = 0; i < 4; i++) {
        int row = r0 + tr * 4 + i;
        int b_  = row >> 11;
        int s   = row & 2047;
        size_t o = (((size_t)(b_ * HH + h)) * SS + s) * DD + d0;
        if (mat == 2) {
            float4 vv;
            vv.x = acc[i][0] + b4[0]; vv.y = acc[i][1] + b4[1];
            vv.z = acc[i][2] + b4[2]; vv.w = acc[i][3] + b4[3];
            *(float4*)(vo + o) = vv;
        } else {
            short4v sv;
            sv.x = f2bf(acc[i][0] + b4[0]); sv.y = f2bf(acc[i][1] + b4[1]);
            sv.z = f2bf(acc[i][2] + b4[2]); sv.w = f2bf(acc[i][3] + b4[3]);
            *(short4v*)(((mat == 0) ? qo : ko) + o) = sv;
        }
    }
}

// ---------------------------------------------------------------------------
// Kernel 2: sliding-window sum of V -> transposed bf16 vsT[bh][d][kk]. (unchanged)
// ---------------------------------------------------------------------------
__global__ __launch_bounds__(256) void vs_kernel(
    const float* __restrict__ v, short* __restrict__ vsT)
{
    const int t   = threadIdx.x;
    const int d4  = t & 7;
    const int kkb = blockIdx.x * 32 + (t >> 3);
    const int bh  = blockIdx.y;
    if (kkb >= 252) return;
    const int kb0 = kkb * 8;

    const float4* vp = (const float4*)(v + ((size_t)bh * SS + kb0) * DD) + d4;
    float4 rbuf[7];
    float4 acc = {0.f, 0.f, 0.f, 0.f};
#pragma unroll
    for (int w = 0; w < WW; w++) {
        float4 xv = vp[w * 8];
        if (w < 7) rbuf[w] = xv;
        acc.x += xv.x; acc.y += xv.y; acc.z += xv.z; acc.w += xv.w;
    }
    short8v sh[4];
    sh[0][0] = f2bf(acc.x); sh[1][0] = f2bf(acc.y);
    sh[2][0] = f2bf(acc.z); sh[3][0] = f2bf(acc.w);
#pragma unroll
    for (int s = 1; s < 8; s++) {
        float4 sub = rbuf[s - 1];
        float4 add = vp[(s + 32) * 8];
        acc.x += add.x - sub.x; acc.y += add.y - sub.y;
        acc.z += add.z - sub.z; acc.w += add.w - sub.w;
        sh[0][s] = f2bf(acc.x); sh[1][s] = f2bf(acc.y);
        sh[2][s] = f2bf(acc.z); sh[3][s] = f2bf(acc.w);
    }
#pragma unroll
    for (int j = 0; j < 4; j++) {
        short* op = vsT + ((size_t)bh * DD + 4 * d4 + j) * KKN + kb0;
        *(short8v*)op = sh[j];
    }
}

// ---------------------------------------------------------------------------
// Kernel 3: flash attention, BK=64 keys/iter (32 iters, 2 barriers each).
//   Kext window 96 rows (128-row ring, 64 staged/iter). Gst[96][72] skewed
//   bf16 Gram (j2 = j - i + 31 in [0,95)). Score via banded-ones U MFMA over
//   6 j'-tiles. PV k=64 (2 chained MFMAs). Junk from clamped K rows provably
//   lands only on globally-masked keys (ki >= (j2+m)-63 >= 32 at kt=31).
// ---------------------------------------------------------------------------
__global__ __launch_bounds__(256, 4) void attn_kernel(
    const short* __restrict__ qg, const short* __restrict__ kg,
    const short* __restrict__ vsTg, float* __restrict__ out)
{
    __shared__ alignas(16) short QbS[64][40];      // Qext; pb union after hoist
    __shared__ alignas(16) short Kb[128][40];      // 128-row K ring
    __shared__ alignas(16) short Gst[96][72];      // bf16 skewed Gram (row 95 = pad)
    __shared__ alignas(16) short vT[2][32][72];    // double-buffered vs tile [d][ki]
    __shared__ float lrow[32];

    short (*Qb)[40] = QbS;
    short (*pb)[72] = (short (*)[72])QbS;   // 32*72 shorts <= 64*40 ✓

    const int t  = threadIdx.x;
    const int qt = blockIdx.x;
    const int bh = blockIdx.y;
    const int q0 = qt * 32;

    const short* qb   = qg   + (size_t)bh * SS * DD;
    const short* kb   = kg   + (size_t)bh * SS * DD;
    const short* vsTb = vsTg + (size_t)bh * DD * KKN;

    const int lane = t & 63, wv = t >> 6;
    const int quad = lane >> 4, lr = lane & 15;
    const int ptm = wv >> 1, ptn = wv & 1;

    // ---- zero-init Gst (garbage containment; unwritten cells stay 0) ----
    {
        short8v z = {0, 0, 0, 0, 0, 0, 0, 0};
        short* g = &Gst[0][0];
        for (int i = t; i < 864; i += 256) *(short8v*)(g + 8 * i) = z;
    }

    // ---- initial staging: Qext 64 rows + K rows 0..127 ----
    {
        int row = t >> 2, c8 = (t & 3) * 8;
        int gq = q0 - 16 + row;
        if (gq >= 0 && gq < SS) {
            *(short8v*)&Qb[row][c8] = *(const short8v*)(qb + (size_t)gq * DD + c8);
        } else {
            float4 z = {0.f, 0.f, 0.f, 0.f};
            *(float4*)&Qb[row][c8] = z;
        }
        *(short8v*)&Kb[row][c8]      = *(const short8v*)(kb + (size_t)row * DD + c8);
        *(short8v*)&Kb[64 + row][c8] = *(const short8v*)(kb + (size_t)(64 + row) * DD + c8);
    }
    if (t < 32) lrow[t] = 0.f;
    __syncthreads();

    // ---- hoist loop-invariant Q B-frags (Qb dead afterwards) ----
    short8v Qf[4];
#pragma unroll
    for (int tq = 0; tq < 4; tq++)
        Qf[tq] = *(const short8v*)&Qb[tq * 16 + lr][quad * 8];

    // ---- banded-ones U-frags: U[m][qi] = 1 iff qi <= m <= qi+32 ----
    short8v Uf[2][2];
#pragma unroll
    for (int qit = 0; qit < 2; qit++)
#pragma unroll
        for (int ch = 0; ch < 2; ch++) {
            short8v u;
#pragma unroll
            for (int j = 0; j < 8; j++) {
                int m  = ch * 32 + quad * 8 + j;
                int qi = qit * 16 + lr;
                u[j] = (qi <= m && m <= qi + 32) ? (short)0x3F80 : (short)0;
            }
            Uf[qit][ch] = u;
        }

    float4v acc = {0.f, 0.f, 0.f, 0.f};
    float lsum[2] = {0.f, 0.f};
    const int npass = (wv < 2) ? 2 : 1;

    for (int kt = 0; kt < 32; kt++) {
        const int k0 = kt * 64;
        // ================= Phase A =================
        // stage vs tile (all 256 threads, 16B each); clamped 16B-aligned tail
        {
            int d_ = t >> 3, c8 = (t & 7) * 8;
            int col = k0 + c8; if (col > KKN - 8) col = KKN - 8;
            *(short8v*)&vT[kt & 1][d_][c8] =
                *(const short8v*)(vsTb + (size_t)d_ * KKN + col);
        }

        // Gram MFMA: wave wv owns K-tiles tk = wv (+4); B = Qf[tq]
        for (int pass = 0; pass < npass; pass++) {
            const int tk = wv + pass * 4;
            const int gr = k0 + tk * 16 + lr;
            const short8v A = *(const short8v*)&Kb[gr & 127][quad * 8];
#pragma unroll
            for (int tq = 0; tq < 4; tq++) {
                const int del = tk - tq;
                if (del < -2 || del > 4) continue;   // dead tile
                float4v c0 = {0.f, 0.f, 0.f, 0.f};
                c0 = __builtin_amdgcn_mfma_f32_16x16x32_bf16(A, Qf[tq], c0, 0, 0, 0);
                const int i = tq * 16 + lr;
#pragma unroll
                for (int e = 0; e < 4; e++) {
                    int j2 = tk * 16 + quad * 4 + e - i + 31;
                    if ((unsigned)j2 < 95u) Gst[j2][i] = f2bf(c0[e]);
                }
            }
        }

        // PV for PREVIOUS iter (k = 64: 2 chained MFMAs)
        if (kt > 0) {
            const short8v Ap0 = *(const short8v*)&pb[ptm * 16 + lr][quad * 8];
            const short8v Ap1 = *(const short8v*)&pb[ptm * 16 + lr][32 + quad * 8];
            const short8v Bv0 = *(const short8v*)&vT[(kt - 1) & 1][ptn * 16 + lr][quad * 8];
            const short8v Bv1 = *(const short8v*)&vT[(kt - 1) & 1][ptn * 16 + lr][32 + quad * 8];
            acc = __builtin_amdgcn_mfma_f32_16x16x32_bf16(Ap0, Bv0, acc, 0, 0, 0);
            acc = __builtin_amdgcn_mfma_f32_16x16x32_bf16(Ap1, Bv1, acc, 0, 0, 0);
        }
        __syncthreads();   // [A] Gst complete; Kb/pb/vT consumed

        // ================= Phase B =================
        // ring prefetch: rows k0+128 .. k0+191 into dead slots (clamped addr)
        if (kt < 31) {
            int r2 = t >> 2, c8 = (t & 3) * 8;
            int g  = k0 + 128 + r2;
            int ga = (g < SS) ? g : (SS - 1);
            *(short8v*)&Kb[g & 127][c8] = *(const short8v*)(kb + (size_t)ga * DD + c8);
        }

        // scores: S_skew = Gst x U; p = exp(S*SCALE - FMAX) -> pb (masked)
        for (int pass = 0; pass < npass; pass++) {
            const int tile = wv + pass * 4;      // j'-tile 0..5
            const int jrow = tile * 16 + lr;
            const short8v A0f = *(const short8v*)&Gst[jrow][quad * 8];
            const short8v A1f = *(const short8v*)&Gst[jrow][32 + quad * 8];
#pragma unroll
            for (int qit = 0; qit < 2; qit++) {
                float4v D = {0.f, 0.f, 0.f, 0.f};
                D = __builtin_amdgcn_mfma_f32_16x16x32_bf16(A0f, Uf[qit][0], D, 0, 0, 0);
                D = __builtin_amdgcn_mfma_f32_16x16x32_bf16(A1f, Uf[qit][1], D, 0, 0, 0);
                const int qi  = qit * 16 + lr;
                const int kib = qi + tile * 16 + quad * 4 - 31;
#pragma unroll
                for (int e = 0; e < 4; e++) {
                    int ki = kib + e;
                    if ((unsigned)ki < 64u) {
                        float p = (k0 + ki < KKN)
                                  ? __expf(fmaf(D[e], SCALE, -FMAX)) : 0.f;
                        pb[qi][ki] = f2bf(p);
                        lsum[qit] += p;
                    }
                }
            }
        }
        __syncthreads();   // [B] pb ready; ring prefetch visible
    }

    // ---- final PV (kt = 31, vT buf 1) ----
    {
        const short8v Ap0 = *(const short8v*)&pb[ptm * 16 + lr][quad * 8];
        const short8v Ap1 = *(const short8v*)&pb[ptm * 16 + lr][32 + quad * 8];
        const short8v Bv0 = *(const short8v*)&vT[1][ptn * 16 + lr][quad * 8];
        const short8v Bv1 = *(const short8v*)&vT[1][ptn * 16 + lr][32 + quad * 8];
        acc = __builtin_amdgcn_mfma_f32_16x16x32_bf16(Ap0, Bv0, acc, 0, 0, 0);
        acc = __builtin_amdgcn_mfma_f32_16x16x32_bf16(Ap1, Bv1, acc, 0, 0, 0);
    }

    // ---- l reduction: cross-quad shuffle then one atomic per (wave, qit) ----
#pragma unroll
    for (int qit = 0; qit < 2; qit++) {
        float s = lsum[qit];
        s += __shfl_xor(s, 16);
        s += __shfl_xor(s, 32);
        if (quad == 0) atomicAdd(&lrow[qit * 16 + lr], s);
    }
    __syncthreads();

    // ---- epilogue ----
    {
        const int rrow = ptm * 16 + quad * 4;
        const int col  = ptn * 16 + lr;
        const int b_ = bh >> 3, h = bh & 7;
#pragma unroll
        for (int e = 0; e < 4; e++) {
            int s_ = q0 + rrow + e;
            out[((size_t)(b_ * SS + s_)) * EE + h * DD + col] = acc[e] / lrow[rrow + e];
        }
    }
}

// ---------------------------------------------------------------------------
extern "C" void kernel_launch(void* const* d_in, const int* in_sizes, int n_in,
                              void* d_out, int out_size, void* d_ws, size_t ws_size,
                              hipStream_t stream)
{
    (void)in_sizes; (void)n_in; (void)out_size; (void)ws_size;
    const float* x  = (const float*)d_in[0];
    const float* Wq = (const float*)d_in[1];
    const float* bq = (const float*)d_in[2];
    const float* Wk = (const float*)d_in[3];
    const float* bk = (const float*)d_in[4];
    const float* Wv = (const float*)d_in[5];
    const float* bv = (const float*)d_in[6];
    float* out = (float*)d_out;

    const size_t REG = (size_t)BB * HH * SS * DD;   // 2,097,152
    short* qbf   = (short*)d_ws;
    short* kbf   = qbf + REG;
    float* vbuf  = (float*)(kbf + REG);
    short* vsTb  = (short*)(vbuf + REG);            // 32*32*2016 shorts

    qkv_kernel<<<dim3(128, 12), dim3(256), 0, stream>>>(x, Wq, bq, Wk, bk, Wv, bv,
                                                        qbf, kbf, vbuf);
    vs_kernel<<<dim3(8, 32), dim3(256), 0, stream>>>(vbuf, vsTb);
    attn_kernel<<<dim3(64, 32), dim3(256), 0, stream>>>(qbf, kbf, vsTb, out);
}